// Round 18
// baseline (41.409 us; speedup 1.0000x reference)
//
#include <hip/hip_runtime.h>
#include <math.h>

// UnrolledMeanShift: B=2, D=32, H=W=256, K=5x5, 3 iterations.
// R18 = R16 (4 thr/pixel, 8ch each, DPP-quad reduce, scaled-space fp16,
// vectorized staging, 25-named-u4v window cache) + ASM REGISTER PIN:
// R16's cache failed not by spilling but by REMATERIALIZATION (VGPR=68,
// ds_reads sunk back into the loop). An empty `asm volatile("":"+v"(..))`
// over all 25 words is an opaque def point -> LLVM must keep them live
// (~100 VGPR cache, ~120-130 total; 128-VGPR step = 16 waves/CU).
// In-loop DS = ZERO; compute becomes VALU-bound (~18 instr/NBODY).
// Scaled space: staged values pre-multiplied by s=sqrt(NC*log2e) so
// |ps-zs|^2 IS the exp2 arg (neg via v_exp input modifier). Final write
// = num*invf/s. Tripwire: VGPR~120 & FETCH~31MB = pin worked.

typedef _Float16 h2  __attribute__((ext_vector_type(2)));
typedef unsigned int u4v __attribute__((ext_vector_type(4)));

constexpr int Dch  = 32;
constexpr int HH   = 256;
constexpr int WW   = 256;
constexpr int BH   = 8;               // tile rows
constexpr int BW   = 16;              // tile cols
constexpr int THs  = 12;              // staged rows (rel -2..9)
constexpr int RSTR = 25;              // staged row stride (24 cols + pad)
constexpr int PSTR = THs * RSTR + 1;  // 301 words plane stride
constexpr int NJOB = 4 * THs * 6;     // 288 staging jobs
constexpr int ITERS = 3;
constexpr int HWp  = HH * WW;
constexpr int NTHR = 512;             // 128 pixels x 4 ch-quarter threads

__device__ __forceinline__ float fdot2f(h2 a, h2 b, float c) {
    return __builtin_amdgcn_fdot2(a, b, c, false);
}

__device__ __forceinline__ float EXP2F(float x) {
#if __has_builtin(__builtin_amdgcn_exp2f)
    return __builtin_amdgcn_exp2f(x);
#else
    return __expf(x * 0.69314718055994531f);
#endif
}

// lane^1 within quad (quad_perm [1,0,3,2])
__device__ __forceinline__ float qswap1(float x) {
    return __int_as_float(
        __builtin_amdgcn_mov_dpp(__float_as_int(x), 0xB1, 0xF, 0xF, true));
}
// lane^2 within quad (quad_perm [2,3,0,1])
__device__ __forceinline__ float qswap2(float x) {
    return __int_as_float(
        __builtin_amdgcn_mov_dpp(__float_as_int(x), 0x4E, 0xF, 0xF, true));
}

__device__ __forceinline__ h2 as_h2(unsigned int x) {
    return __builtin_bit_cast(h2, x);
}

__device__ __forceinline__ h2 pk2(float a, float b) {
#if __has_builtin(__builtin_amdgcn_cvt_pkrtz)
    return __builtin_bit_cast(h2, __builtin_amdgcn_cvt_pkrtz(a, b));
#else
    h2 r; r[0] = (_Float16)a; r[1] = (_Float16)b; return r;
#endif
}

__device__ __forceinline__ unsigned int pku(float a, float b) {
    return __builtin_bit_cast(unsigned int, pk2(a, b));
}

__global__ __launch_bounds__(NTHR, 2)
void meanshift_kernel(const float* __restrict__ E,
                      const float* __restrict__ lbw,
                      float* __restrict__ out)
{
    __shared__ u4v tile[4 * PSTR];       // 19.3 KB (fp16 scaled, 8ch/16B)

    const int bz  = blockIdx.z;
    const int oh  = blockIdx.y * BH - 2;       // staged row 0 = rel -2
    const int owc = blockIdx.x * BW;
    const int gw0 = owc - 4;                   // staged col 0 = rel -4
    const int tid = threadIdx.x;
    const int cq  = tid & 3;                   // channel quarter (DPP quad)
    const int idx = tid >> 2;                  // 0..127 pixel in tile
    const int px  = idx & (BW - 1);
    const int py  = idx >> 4;

    const float bwv = log1pf(__expf(lbw[0]));      // softplus
    const float cc2 = 1.0f / (2.0f * bwv * bwv);
    const float NCf = cc2 * 1.44269504f;           // w = 2^(-NC*dist^2)
    const float scl = __builtin_sqrtf(NCf);        // scaled space
    const float isc = 1.0f / scl;

    const float* Eb = E + (size_t)bz * Dch * HWp;

    // ---- vectorized staging (R15), pre-scaled by scl ----
    if (tid < NJOB) {
        const int cc  = tid / (THs * 6);
        const int rem = tid - cc * (THs * 6);
        const int row = rem / 6;
        const int g   = rem - row * 6;
        const int gh  = oh + row;
        const int gwb = gw0 + 4 * g;

        float4 F0 = {0.f,0.f,0.f,0.f}, F1 = F0, F2 = F0, F3 = F0;
        float4 F4 = F0, F5 = F0, F6 = F0, F7 = F0;
        if ((unsigned)gh < (unsigned)HH) {
            const float* base = Eb + (size_t)(8 * cc) * HWp + gh * WW;
            if (gwb >= 0 && gwb + 4 <= WW) {       // aligned fast path
                F0 = *(const float4*)(base + 0 * (size_t)HWp + gwb);
                F1 = *(const float4*)(base + 1 * (size_t)HWp + gwb);
                F2 = *(const float4*)(base + 2 * (size_t)HWp + gwb);
                F3 = *(const float4*)(base + 3 * (size_t)HWp + gwb);
                F4 = *(const float4*)(base + 4 * (size_t)HWp + gwb);
                F5 = *(const float4*)(base + 5 * (size_t)HWp + gwb);
                F6 = *(const float4*)(base + 6 * (size_t)HWp + gwb);
                F7 = *(const float4*)(base + 7 * (size_t)HWp + gwb);
            } else {                                // edge: per-element
                const bool i0 = (unsigned)(gwb + 0) < (unsigned)WW;
                const bool i1 = (unsigned)(gwb + 1) < (unsigned)WW;
                const bool i2 = (unsigned)(gwb + 2) < (unsigned)WW;
                const bool i3 = (unsigned)(gwb + 3) < (unsigned)WW;
#define GE(K) F##K = make_float4( \
                    i0 ? base[(K) * (size_t)HWp + gwb + 0] : 0.f, \
                    i1 ? base[(K) * (size_t)HWp + gwb + 1] : 0.f, \
                    i2 ? base[(K) * (size_t)HWp + gwb + 2] : 0.f, \
                    i3 ? base[(K) * (size_t)HWp + gwb + 3] : 0.f)
                GE(0); GE(1); GE(2); GE(3); GE(4); GE(5); GE(6); GE(7);
#undef GE
            }
        }
        const int wbase = cc * PSTR + row * RSTR + 4 * g;
        u4v W;
        W[0]=pku(F0.x*scl,F1.x*scl); W[1]=pku(F2.x*scl,F3.x*scl);
        W[2]=pku(F4.x*scl,F5.x*scl); W[3]=pku(F6.x*scl,F7.x*scl);
        tile[wbase + 0] = W;
        W[0]=pku(F0.y*scl,F1.y*scl); W[1]=pku(F2.y*scl,F3.y*scl);
        W[2]=pku(F4.y*scl,F5.y*scl); W[3]=pku(F6.y*scl,F7.y*scl);
        tile[wbase + 1] = W;
        W[0]=pku(F0.z*scl,F1.z*scl); W[1]=pku(F2.z*scl,F3.z*scl);
        W[2]=pku(F4.z*scl,F5.z*scl); W[3]=pku(F6.z*scl,F7.z*scl);
        tile[wbase + 2] = W;
        W[0]=pku(F0.w*scl,F1.w*scl); W[1]=pku(F2.w*scl,F3.w*scl);
        W[2]=pku(F4.w*scl,F5.w*scl); W[3]=pku(F6.w*scl,F7.w*scl);
        tile[wbase + 3] = W;
    }
    __syncthreads();

    const u4v* __restrict__ tP = tile + cq * PSTR;   // my 8-channel plane

    // ---- fill the 25-word register cache (named SSA) ----
    const int rb0 = (py + 0) * RSTR + (px + 2);
    const int rb1 = rb0 + RSTR;
    const int rb2 = rb1 + RSTR;
    const int rb3 = rb2 + RSTR;
    const int rb4 = rb3 + RSTR;
    u4v c00 = tP[rb0+0], c01 = tP[rb0+1], c02 = tP[rb0+2], c03 = tP[rb0+3], c04 = tP[rb0+4];
    u4v c10 = tP[rb1+0], c11 = tP[rb1+1], c12 = tP[rb1+2], c13 = tP[rb1+3], c14 = tP[rb1+4];
    u4v c20 = tP[rb2+0], c21 = tP[rb2+1], c22 = tP[rb2+2], c23 = tP[rb2+3], c24 = tP[rb2+4];
    u4v c30 = tP[rb3+0], c31 = tP[rb3+1], c32 = tP[rb3+2], c33 = tP[rb3+3], c34 = tP[rb3+4];
    u4v c40 = tP[rb4+0], c41 = tP[rb4+1], c42 = tP[rb4+2], c43 = tP[rb4+3], c44 = tP[rb4+4];

    // PIN: opaque def point -> compiler cannot rematerialize the ds_reads.
    asm volatile("" :
        "+v"(c00), "+v"(c01), "+v"(c02), "+v"(c03), "+v"(c04),
        "+v"(c10), "+v"(c11), "+v"(c12), "+v"(c13), "+v"(c14),
        "+v"(c20), "+v"(c21), "+v"(c22), "+v"(c23), "+v"(c24),
        "+v"(c30), "+v"(c31), "+v"(c32), "+v"(c33), "+v"(c34),
        "+v"(c40), "+v"(c41), "+v"(c42), "+v"(c43), "+v"(c44));

    // ---- init z (scaled) = own pixel (center c22), my 8 channels ----
    h2 z0 = as_h2(c22[0]), z1 = as_h2(c22[1]);
    h2 z2 = as_h2(c22[2]), z3 = as_h2(c22[3]);

    float* Ob = out + (size_t)bz * Dch * HWp;
    const int off    = (oh + 2 + py) * WW + (owc + px);
    const int chbase = 8 * cq;

#define NBODY(Q) do {                                                         \
        const h2 p0 = as_h2(Q[0]), p1 = as_h2(Q[1]);                          \
        const h2 p2 = as_h2(Q[2]), p3 = as_h2(Q[3]);                          \
        const h2 e0 = p0 - z0, e1 = p1 - z1;                                  \
        const h2 e2 = p2 - z2, e3 = p3 - z3;                                  \
        float s0 = fdot2f(e0, e0, 0.f);                                       \
        float s1 = fdot2f(e1, e1, 0.f);                                       \
        s0 = fdot2f(e2, e2, s0);                                              \
        s1 = fdot2f(e3, e3, s1);                                              \
        const float dp = s0 + s1;             /* my 8 ch (scaled) */          \
        const float d2 = dp + qswap1(dp);                                     \
        const float d4 = d2 + qswap2(d2);     /* full 32 ch */                \
        const float w  = EXP2F(-d4);          /* neg folds into v_exp */      \
        den += w;                                                             \
        const h2 w2v = pk2(w, w);                                             \
        n0 += p0 * w2v; n1 += p1 * w2v;                                       \
        n2 += p2 * w2v; n3 += p3 * w2v;                                       \
    } while (0)

    #pragma unroll 1
    for (int it = 0; it < ITERS; ++it) {
        h2 n0 = {(_Float16)0.f, (_Float16)0.f};
        h2 n1 = n0, n2 = n0, n3 = n0;
        float den = 0.f;

        NBODY(c00); NBODY(c01); NBODY(c02); NBODY(c03); NBODY(c04);
        NBODY(c10); NBODY(c11); NBODY(c12); NBODY(c13); NBODY(c14);
        NBODY(c20); NBODY(c21); NBODY(c22); NBODY(c23); NBODY(c24);
        NBODY(c30); NBODY(c31); NBODY(c32); NBODY(c33); NBODY(c34);
        NBODY(c40); NBODY(c41); NBODY(c42); NBODY(c43); NBODY(c44);

        const float invf = 1.0f / (den + 1e-6f);
        if (it == ITERS - 1) {
            const float fin = invf * isc;     // unscale on the way out
#define WR(IDX, NV, EL) Ob[(size_t)(chbase + (IDX)) * HWp + off] = (float)NV[EL] * fin
            WR(0, n0, 0); WR(1, n0, 1); WR(2, n1, 0); WR(3, n1, 1);
            WR(4, n2, 0); WR(5, n2, 1); WR(6, n3, 0); WR(7, n3, 1);
#undef WR
        } else {
            const h2 iv = pk2(invf, invf);    // stays in scaled space
            z0 = n0 * iv; z1 = n1 * iv; z2 = n2 * iv; z3 = n3 * iv;
        }
    }
#undef NBODY
}

extern "C" void kernel_launch(void* const* d_in, const int* in_sizes, int n_in,
                              void* d_out, int out_size, void* d_ws, size_t ws_size,
                              hipStream_t stream) {
    const float* E   = (const float*)d_in[0];
    const float* lbw = (const float*)d_in[1];
    float* out       = (float*)d_out;

    const int B = in_sizes[0] / (Dch * HWp);       // = 2
    dim3 grid(WW / BW, HH / BH, B);                // (16,32,2) = 1024 blocks
    dim3 block(NTHR, 1, 1);                        // 512 threads (4/pixel)
    hipLaunchKernelGGL(meanshift_kernel, grid, block, 0, stream, E, lbw, out);
}

// Round 19
// 39.069 us; speedup vs baseline: 1.0599x; 1.0599x over previous
//
#include <hip/hip_runtime.h>
#include <math.h>

// UnrolledMeanShift: B=2, D=32, H=W=256, K=5x5, 3 iterations.
// R19 = 4-way channel split x VERTICAL-PAIR sharing: the only combination
// that cuts wave-level DS ~2x (pair-share, R8/R17) while KEEPING 16 waves/CU
// (4 thr-quarters/px keeps total threads at 262144; R8/R17 halved threads
// -> 8 waves/CU -> latency-bound). Per thread: 8 channels x 2 vertical px;
// per 6-row group, 5 b128 reads of MY plane feed both pixels' 5 NBODYs.
// Wave-DS/iter: 30 b128 = 360 cyc vs R15's 745. Direct |p-z|^2 in SCALED
// space (pre-multiplied by s=sqrt(NC*log2e), R16-validated): no sqv array,
// no S reads; w = exp2(-d4) via v_exp input modifier. Dist reduced over the
// DPP quad (lane^1 then lane^2). All named SSA (scratch lessons R4-R6).

typedef _Float16 h2  __attribute__((ext_vector_type(2)));
typedef unsigned int u4v __attribute__((ext_vector_type(4)));

constexpr int Dch  = 32;
constexpr int HH   = 256;
constexpr int WW   = 256;
constexpr int BH   = 16;              // tile rows (8 vertical pairs)
constexpr int BW   = 16;              // tile cols
constexpr int THs  = 20;              // staged rows (rel -2..17)
constexpr int RSTR = 25;              // staged row stride (24 cols + pad)
constexpr int PSTR = THs * RSTR + 1;  // 501 words plane stride
constexpr int NJOB = 4 * THs * 6;     // 480 staging jobs
constexpr int ITERS = 3;
constexpr int HWp  = HH * WW;
constexpr int NTHR = 512;             // 4 cq x 128 px-pairs

__device__ __forceinline__ float fdot2f(h2 a, h2 b, float c) {
    return __builtin_amdgcn_fdot2(a, b, c, false);
}

__device__ __forceinline__ float EXP2F(float x) {
#if __has_builtin(__builtin_amdgcn_exp2f)
    return __builtin_amdgcn_exp2f(x);
#else
    return __expf(x * 0.69314718055994531f);
#endif
}

// lane^1 within quad (quad_perm [1,0,3,2])
__device__ __forceinline__ float qswap1(float x) {
    return __int_as_float(
        __builtin_amdgcn_mov_dpp(__float_as_int(x), 0xB1, 0xF, 0xF, true));
}
// lane^2 within quad (quad_perm [2,3,0,1])
__device__ __forceinline__ float qswap2(float x) {
    return __int_as_float(
        __builtin_amdgcn_mov_dpp(__float_as_int(x), 0x4E, 0xF, 0xF, true));
}

__device__ __forceinline__ h2 as_h2(unsigned int x) {
    return __builtin_bit_cast(h2, x);
}

__device__ __forceinline__ h2 pk2(float a, float b) {
#if __has_builtin(__builtin_amdgcn_cvt_pkrtz)
    return __builtin_bit_cast(h2, __builtin_amdgcn_cvt_pkrtz(a, b));
#else
    h2 r; r[0] = (_Float16)a; r[1] = (_Float16)b; return r;
#endif
}

__device__ __forceinline__ unsigned int pku(float a, float b) {
    return __builtin_bit_cast(unsigned int, pk2(a, b));
}

__global__ __launch_bounds__(NTHR, 2)
void meanshift_kernel(const float* __restrict__ E,
                      const float* __restrict__ lbw,
                      float* __restrict__ out)
{
    __shared__ u4v tile[4 * PSTR];       // 32.1 KB (fp16 scaled, 8ch/16B)

    const int bz  = blockIdx.z;
    const int oh  = blockIdx.y * BH - 2;       // staged row 0 = rel -2
    const int owc = blockIdx.x * BW;
    const int gw0 = owc - 4;                   // staged col 0 = rel -4
    const int tid = threadIdx.x;
    const int cq  = tid & 3;                   // channel quarter (DPP quad)
    const int idx = tid >> 2;                  // 0..127 pixel-pair
    const int px  = idx & (BW - 1);
    const int pyy = idx >> 4;                  // 0..7
    const int py0 = 2 * pyy;                   // upper pixel row (A)

    const float bwv = log1pf(__expf(lbw[0]));      // softplus
    const float cc2 = 1.0f / (2.0f * bwv * bwv);
    const float NCf = cc2 * 1.44269504f;           // w = 2^(-NC*dist^2)
    const float scl = __builtin_sqrtf(NCf);        // scaled space
    const float isc = 1.0f / scl;

    const float* Eb = E + (size_t)bz * Dch * HWp;

    // ---- vectorized staging (R15), pre-scaled by scl ----
    if (tid < NJOB) {
        const int cc  = tid / (THs * 6);
        const int rem = tid - cc * (THs * 6);
        const int row = rem / 6;
        const int g   = rem - row * 6;
        const int gh  = oh + row;
        const int gwb = gw0 + 4 * g;

        float4 F0 = {0.f,0.f,0.f,0.f}, F1 = F0, F2 = F0, F3 = F0;
        float4 F4 = F0, F5 = F0, F6 = F0, F7 = F0;
        if ((unsigned)gh < (unsigned)HH) {
            const float* base = Eb + (size_t)(8 * cc) * HWp + gh * WW;
            if (gwb >= 0 && gwb + 4 <= WW) {       // aligned fast path
                F0 = *(const float4*)(base + 0 * (size_t)HWp + gwb);
                F1 = *(const float4*)(base + 1 * (size_t)HWp + gwb);
                F2 = *(const float4*)(base + 2 * (size_t)HWp + gwb);
                F3 = *(const float4*)(base + 3 * (size_t)HWp + gwb);
                F4 = *(const float4*)(base + 4 * (size_t)HWp + gwb);
                F5 = *(const float4*)(base + 5 * (size_t)HWp + gwb);
                F6 = *(const float4*)(base + 6 * (size_t)HWp + gwb);
                F7 = *(const float4*)(base + 7 * (size_t)HWp + gwb);
            } else {                                // edge: per-element
                const bool i0 = (unsigned)(gwb + 0) < (unsigned)WW;
                const bool i1 = (unsigned)(gwb + 1) < (unsigned)WW;
                const bool i2 = (unsigned)(gwb + 2) < (unsigned)WW;
                const bool i3 = (unsigned)(gwb + 3) < (unsigned)WW;
#define GE(K) F##K = make_float4( \
                    i0 ? base[(K) * (size_t)HWp + gwb + 0] : 0.f, \
                    i1 ? base[(K) * (size_t)HWp + gwb + 1] : 0.f, \
                    i2 ? base[(K) * (size_t)HWp + gwb + 2] : 0.f, \
                    i3 ? base[(K) * (size_t)HWp + gwb + 3] : 0.f)
                GE(0); GE(1); GE(2); GE(3); GE(4); GE(5); GE(6); GE(7);
#undef GE
            }
        }
        const int wbase = cc * PSTR + row * RSTR + 4 * g;
        u4v W;
        W[0]=pku(F0.x*scl,F1.x*scl); W[1]=pku(F2.x*scl,F3.x*scl);
        W[2]=pku(F4.x*scl,F5.x*scl); W[3]=pku(F6.x*scl,F7.x*scl);
        tile[wbase + 0] = W;
        W[0]=pku(F0.y*scl,F1.y*scl); W[1]=pku(F2.y*scl,F3.y*scl);
        W[2]=pku(F4.y*scl,F5.y*scl); W[3]=pku(F6.y*scl,F7.y*scl);
        tile[wbase + 1] = W;
        W[0]=pku(F0.z*scl,F1.z*scl); W[1]=pku(F2.z*scl,F3.z*scl);
        W[2]=pku(F4.z*scl,F5.z*scl); W[3]=pku(F6.z*scl,F7.z*scl);
        tile[wbase + 2] = W;
        W[0]=pku(F0.w*scl,F1.w*scl); W[1]=pku(F2.w*scl,F3.w*scl);
        W[2]=pku(F4.w*scl,F5.w*scl); W[3]=pku(F6.w*scl,F7.w*scl);
        tile[wbase + 3] = W;
    }
    __syncthreads();

    const u4v* __restrict__ tP = tile + cq * PSTR;   // my 8-channel plane

    // ---- init z (scaled) for both pixels of the pair ----
    h2 zA0, zA1, zA2, zA3, zB0, zB1, zB2, zB3;
    {
        const int mypA = (py0 + 2) * RSTR + (px + 4);
        const u4v ca = tP[mypA];
        const u4v cb = tP[mypA + RSTR];
        zA0 = as_h2(ca[0]); zA1 = as_h2(ca[1]);
        zA2 = as_h2(ca[2]); zA3 = as_h2(ca[3]);
        zB0 = as_h2(cb[0]); zB1 = as_h2(cb[1]);
        zB2 = as_h2(cb[2]); zB3 = as_h2(cb[3]);
    }

    float* Ob = out + (size_t)bz * Dch * HWp;
    const int offA   = (oh + 2 + py0) * WW + (owc + px);
    const int chbase = 8 * cq;

// one neighbor (4 named h2 = 8 channels) against pixel ZP -> NP/DEN
#define NB(P0,P1,P2,P3, ZP, NP, DEN) do {                                     \
        const h2 e0 = P0 - ZP##0, e1 = P1 - ZP##1;                            \
        const h2 e2 = P2 - ZP##2, e3 = P3 - ZP##3;                            \
        float s0 = fdot2f(e0, e0, 0.f);                                       \
        float s1 = fdot2f(e1, e1, 0.f);                                       \
        s0 = fdot2f(e2, e2, s0);                                              \
        s1 = fdot2f(e3, e3, s1);                                              \
        const float dp = s0 + s1;             /* my 8 ch (scaled) */          \
        const float d2 = dp + qswap1(dp);                                     \
        const float d4 = d2 + qswap2(d2);     /* full 32 ch */                \
        const float w  = EXP2F(-d4);                                          \
        DEN += w;                                                             \
        const h2 w2v = pk2(w, w);                                             \
        NP##0 += P0 * w2v; NP##1 += P1 * w2v;                                 \
        NP##2 += P2 * w2v; NP##3 += P3 * w2v;                                 \
    } while (0)

    #pragma unroll 1
    for (int it = 0; it < ITERS; ++it) {
        h2 nA0 = {(_Float16)0.f, (_Float16)0.f};
        h2 nA1 = nA0, nA2 = nA0, nA3 = nA0;
        h2 nB0 = nA0, nB1 = nA0, nB2 = nA0, nB3 = nA0;
        float denA = 0.f, denB = 0.f;

        #pragma unroll 1
        for (int di = 0; di < 6; ++di) {
            const int rw = (py0 + di) * RSTR + (px + 2);
            // shared reads: 5 words of MY plane (once for both pixels)
            const u4v q0 = tP[rw + 0];
            const u4v q1 = tP[rw + 1];
            const u4v q2 = tP[rw + 2];
            const u4v q3 = tP[rw + 3];
            const u4v q4 = tP[rw + 4];
            const h2 p00 = as_h2(q0[0]), p01 = as_h2(q0[1]), p02 = as_h2(q0[2]), p03 = as_h2(q0[3]);
            const h2 p10 = as_h2(q1[0]), p11 = as_h2(q1[1]), p12 = as_h2(q1[2]), p13 = as_h2(q1[3]);
            const h2 p20 = as_h2(q2[0]), p21 = as_h2(q2[1]), p22 = as_h2(q2[2]), p23 = as_h2(q2[3]);
            const h2 p30 = as_h2(q3[0]), p31 = as_h2(q3[1]), p32 = as_h2(q3[2]), p33 = as_h2(q3[3]);
            const h2 p40 = as_h2(q4[0]), p41 = as_h2(q4[1]), p42 = as_h2(q4[2]), p43 = as_h2(q4[3]);
            if (di != 5) {   // rows 0..4 feed pixel A
                NB(p00,p01,p02,p03, zA, nA, denA);
                NB(p10,p11,p12,p13, zA, nA, denA);
                NB(p20,p21,p22,p23, zA, nA, denA);
                NB(p30,p31,p32,p33, zA, nA, denA);
                NB(p40,p41,p42,p43, zA, nA, denA);
            }
            if (di != 0) {   // rows 1..5 feed pixel B
                NB(p00,p01,p02,p03, zB, nB, denB);
                NB(p10,p11,p12,p13, zB, nB, denB);
                NB(p20,p21,p22,p23, zB, nB, denB);
                NB(p30,p31,p32,p33, zB, nB, denB);
                NB(p40,p41,p42,p43, zB, nB, denB);
            }
        }

        const float invA = 1.0f / (denA + 1e-6f);
        const float invB = 1.0f / (denB + 1e-6f);
        if (it == ITERS - 1) {
            const float finA = invA * isc;    // unscale on the way out
            const float finB = invB * isc;
#define WR(IDX, NV, EL, OFF, INV) \
            Ob[(size_t)(chbase + (IDX)) * HWp + (OFF)] = (float)NV[EL] * (INV)
            WR(0, nA0, 0, offA, finA); WR(1, nA0, 1, offA, finA);
            WR(2, nA1, 0, offA, finA); WR(3, nA1, 1, offA, finA);
            WR(4, nA2, 0, offA, finA); WR(5, nA2, 1, offA, finA);
            WR(6, nA3, 0, offA, finA); WR(7, nA3, 1, offA, finA);
            WR(0, nB0, 0, offA + WW, finB); WR(1, nB0, 1, offA + WW, finB);
            WR(2, nB1, 0, offA + WW, finB); WR(3, nB1, 1, offA + WW, finB);
            WR(4, nB2, 0, offA + WW, finB); WR(5, nB2, 1, offA + WW, finB);
            WR(6, nB3, 0, offA + WW, finB); WR(7, nB3, 1, offA + WW, finB);
#undef WR
        } else {
            const h2 ivA = pk2(invA, invA);   // stays in scaled space
            const h2 ivB = pk2(invB, invB);
            zA0 = nA0 * ivA; zA1 = nA1 * ivA; zA2 = nA2 * ivA; zA3 = nA3 * ivA;
            zB0 = nB0 * ivB; zB1 = nB1 * ivB; zB2 = nB2 * ivB; zB3 = nB3 * ivB;
        }
    }
#undef NB
}

extern "C" void kernel_launch(void* const* d_in, const int* in_sizes, int n_in,
                              void* d_out, int out_size, void* d_ws, size_t ws_size,
                              hipStream_t stream) {
    const float* E   = (const float*)d_in[0];
    const float* lbw = (const float*)d_in[1];
    float* out       = (float*)d_out;

    const int B = in_sizes[0] / (Dch * HWp);       // = 2
    dim3 grid(WW / BW, HH / BH, B);                // (16,16,2) = 512 blocks
    dim3 block(NTHR, 1, 1);                        // 512 thr (4/px, 2px ea)
    hipLaunchKernelGGL(meanshift_kernel, grid, block, 0, stream, E, lbw, out);
}